// Round 1
// baseline (539.265 us; speedup 1.0000x reference)
//
#include <hip/hip_runtime.h>
#include <hip/hip_bf16.h>
#include <stdint.h>

typedef __bf16 bf16;
typedef bf16 bf16x8 __attribute__((ext_vector_type(8)));
typedef float f32x4 __attribute__((ext_vector_type(4)));

#define N_NODES 50000
#define FEAT 128

static constexpr size_t INBOX_BYTES = (size_t)N_NODES * FEAT * 4;   // 25.6 MB f32 inbox
static constexpr size_t UV_BYTES    = (size_t)N_NODES * 256 * 2;    // 25.6 MB bf16 uv

// weight table element offsets (bf16 elements) within ws weight region
#define WUV_OFF 0        // [256][128]  combined (mw1 top|bottom) transposed
#define WM2_OFF 32768    // [128][128]
#define WM3_OFF 49152    // [128][128]
#define WN1_OFF 65536    // [128][256]
#define WN2_OFF 98304    // [128][128]
#define WN3_OFF 114688   // [128][128]
#define W_TOTAL 131072

__device__ __forceinline__ bf16x8 cvt_f32x8_bf16(const float* __restrict__ p) {
  float4 f0 = *(const float4*)p;
  float4 f1 = *(const float4*)(p + 4);
  bf16x8 t;
  t[0] = (bf16)f0.x; t[1] = (bf16)f0.y; t[2] = (bf16)f0.z; t[3] = (bf16)f0.w;
  t[4] = (bf16)f1.x; t[5] = (bf16)f1.y; t[6] = (bf16)f1.z; t[7] = (bf16)f1.w;
  return t;
}

// ---------------- prep: cast+transpose weights to bf16 ----------------
__global__ void prep_weights_kernel(const float* __restrict__ mw1, const float* __restrict__ mw2,
                                    const float* __restrict__ mw3, const float* __restrict__ nw1,
                                    const float* __restrict__ nw2, const float* __restrict__ nw3,
                                    bf16* __restrict__ w) {
  int i = blockIdx.x * blockDim.x + threadIdx.x;
  if (i >= W_TOTAL) return;
  float v;
  if (i < WM2_OFF) {            // wuv_t[c][k], c in [0,256), k in [0,128)
    int c = i >> 7, k = i & 127;
    v = (c < 128) ? mw1[k * 128 + c] : mw1[(128 + k) * 128 + (c - 128)];
  } else if (i < WM3_OFF) {     // wm2_t[c][k]
    int j = i - WM2_OFF; int c = j >> 7, k = j & 127;
    v = mw2[k * 128 + c];
  } else if (i < WN1_OFF) {     // wm3_t[c][k]
    int j = i - WM3_OFF; int c = j >> 7, k = j & 127;
    v = mw3[k * 128 + c];
  } else if (i < WN2_OFF) {     // wn1_t[c][k], k in [0,256)
    int j = i - WN1_OFF; int c = j >> 8, k = j & 255;
    v = nw1[k * 128 + c];
  } else if (i < WN3_OFF) {     // wn2_t[c][k]
    int j = i - WN2_OFF; int c = j >> 7, k = j & 127;
    v = nw2[k * 128 + c];
  } else {                      // wn3_t[c][k]
    int j = i - WN3_OFF; int c = j >> 7, k = j & 127;
    v = nw3[k * 128 + c];
  }
  w[i] = (bf16)v;
}

// ---------------- uv = nodes @ [W1a | W1b] (+b1 on u-half), bf16 out ----------------
// block: 512 thr = 8 waves as 2(M)x4(N); tile 128 rows x 256 cols; wave 64x64; frag 16x16x32
__global__ __launch_bounds__(512) void uv_gemm_kernel(const float* __restrict__ nodes,
                                                      const bf16* __restrict__ wuvt,
                                                      const float* __restrict__ mb1,
                                                      bf16* __restrict__ uv) {
  const int tid = threadIdx.x;
  const int lane = tid & 63, wid = tid >> 6;
  const int wm = wid >> 2, wn = wid & 3;
  const int rBase = blockIdx.x * 128 + wm * 64;
  const int cBase = wn * 64;
  const int l15 = lane & 15, ka = (lane >> 4) * 8, rj = (lane >> 4) * 4;

  f32x4 acc[4][4];
#pragma unroll
  for (int mi = 0; mi < 4; ++mi)
#pragma unroll
    for (int ni = 0; ni < 4; ++ni) acc[mi][ni] = (f32x4){0.f, 0.f, 0.f, 0.f};

#pragma unroll
  for (int kk = 0; kk < 4; ++kk) {
    const int k0 = kk * 32 + ka;
    bf16x8 a[4], b[4];
#pragma unroll
    for (int mi = 0; mi < 4; ++mi) {
      int r = rBase + mi * 16 + l15;
      if (r > N_NODES - 1) r = N_NODES - 1;
      a[mi] = cvt_f32x8_bf16(nodes + (size_t)r * FEAT + k0);
    }
#pragma unroll
    for (int ni = 0; ni < 4; ++ni) {
      int c = cBase + ni * 16 + l15;
      b[ni] = *(const bf16x8*)(wuvt + (size_t)c * 128 + k0);
    }
#pragma unroll
    for (int mi = 0; mi < 4; ++mi)
#pragma unroll
      for (int ni = 0; ni < 4; ++ni)
        acc[mi][ni] = __builtin_amdgcn_mfma_f32_16x16x32_bf16(a[mi], b[ni], acc[mi][ni], 0, 0, 0);
  }
#pragma unroll
  for (int mi = 0; mi < 4; ++mi)
#pragma unroll
    for (int ni = 0; ni < 4; ++ni) {
      int c = cBase + ni * 16 + l15;
      float bias = (c < FEAT) ? mb1[c] : 0.f;  // fold b1 into u-half
#pragma unroll
      for (int j = 0; j < 4; ++j) {
        int r = rBase + mi * 16 + rj + j;
        if (r < N_NODES) uv[(size_t)r * 256 + c] = (bf16)(acc[mi][ni][j] + bias);
      }
    }
}

// ---------------- edge kernel: h1 = relu(u[recv]+v[send]); 2 MFMA layers; atomic scatter ----
// block: 512 thr = 8 waves as 4(M)x2(N); 256 edges x 128 cols; wave 64x64
__global__ __launch_bounds__(512) void edge_kernel(const bf16* __restrict__ uv,
                                                   const int* __restrict__ senders,
                                                   const int* __restrict__ receivers,
                                                   const bf16* __restrict__ wm2t,
                                                   const bf16* __restrict__ wm3t,
                                                   const float* __restrict__ mb2,
                                                   const float* __restrict__ mb3,
                                                   float* __restrict__ inbox, int E) {
  __shared__ bf16 h1[256 * 128];  // 64 KB, XOR-swizzled rows
  __shared__ bf16 h2[256 * 128];  // 64 KB
  __shared__ int rIds[256];
  __shared__ int sIds[256];

  const int tid = threadIdx.x;
  const int e0 = blockIdx.x * 256;
  const int rMax = (E - e0 < 256) ? (E - e0) : 256;

  if (tid < 256) {
    int e = e0 + tid; if (e >= E) e = E - 1;
    rIds[tid] = receivers[e];
  } else {
    int e = e0 + tid - 256; if (e >= E) e = E - 1;
    sIds[tid - 256] = senders[e];
  }
  __syncthreads();

  // build h1: 256 rows x 128 cols, 8-elem chunks; 4096 chunks / 512 thr = 8 each
#pragma unroll
  for (int i = 0; i < 8; ++i) {
    int idx = tid + i * 512;
    int r = idx >> 4, ch = (idx & 15) * 8;
    int recv = rIds[r], send = sIds[r];
    bf16x8 ur = *(const bf16x8*)(uv + (size_t)recv * 256 + ch);
    bf16x8 vs = *(const bf16x8*)(uv + (size_t)send * 256 + 128 + ch);
    bf16x8 h;
#pragma unroll
    for (int t = 0; t < 8; ++t) {
      float x = (float)ur[t] + (float)vs[t];
      h[t] = (bf16)(x > 0.f ? x : 0.f);
    }
    int byte = r * 256 + ((ch * 2) ^ ((r & 7) << 4));
    *(bf16x8*)((char*)h1 + byte) = h;
  }
  __syncthreads();

  const int lane = tid & 63, wid = tid >> 6;
  const int wm = wid >> 1, wn = wid & 1;
  const int rBase = wm * 64, cBase = wn * 64;
  const int l15 = lane & 15, ka = (lane >> 4) * 8, rj = (lane >> 4) * 4;

  f32x4 acc[4][4];
  // ---- layer 2: h2 = relu(h1 @ W2 + b2) ----
#pragma unroll
  for (int mi = 0; mi < 4; ++mi)
#pragma unroll
    for (int ni = 0; ni < 4; ++ni) acc[mi][ni] = (f32x4){0.f, 0.f, 0.f, 0.f};
#pragma unroll
  for (int kk = 0; kk < 4; ++kk) {
    const int k0 = kk * 32 + ka;
    bf16x8 a[4], b[4];
#pragma unroll
    for (int mi = 0; mi < 4; ++mi) {
      int r = rBase + mi * 16 + l15;
      int byte = r * 256 + ((k0 * 2) ^ ((r & 7) << 4));
      a[mi] = *(const bf16x8*)((const char*)h1 + byte);
    }
#pragma unroll
    for (int ni = 0; ni < 4; ++ni) {
      int c = cBase + ni * 16 + l15;
      b[ni] = *(const bf16x8*)(wm2t + (size_t)c * 128 + k0);
    }
#pragma unroll
    for (int mi = 0; mi < 4; ++mi)
#pragma unroll
      for (int ni = 0; ni < 4; ++ni)
        acc[mi][ni] = __builtin_amdgcn_mfma_f32_16x16x32_bf16(a[mi], b[ni], acc[mi][ni], 0, 0, 0);
  }
#pragma unroll
  for (int mi = 0; mi < 4; ++mi)
#pragma unroll
    for (int ni = 0; ni < 4; ++ni) {
      int c = cBase + ni * 16 + l15;
      float bias = mb2[c];
#pragma unroll
      for (int j = 0; j < 4; ++j) {
        int r = rBase + mi * 16 + rj + j;
        float v = acc[mi][ni][j] + bias;
        v = v > 0.f ? v : 0.f;
        int byte = r * 256 + ((c * 2) ^ ((r & 7) << 4));
        *(bf16*)((char*)h2 + byte) = (bf16)v;
      }
    }
  __syncthreads();

  // ---- layer 3: msg = h2 @ W3 + b3; atomic scatter to inbox[recv] ----
#pragma unroll
  for (int mi = 0; mi < 4; ++mi)
#pragma unroll
    for (int ni = 0; ni < 4; ++ni) acc[mi][ni] = (f32x4){0.f, 0.f, 0.f, 0.f};
#pragma unroll
  for (int kk = 0; kk < 4; ++kk) {
    const int k0 = kk * 32 + ka;
    bf16x8 a[4], b[4];
#pragma unroll
    for (int mi = 0; mi < 4; ++mi) {
      int r = rBase + mi * 16 + l15;
      int byte = r * 256 + ((k0 * 2) ^ ((r & 7) << 4));
      a[mi] = *(const bf16x8*)((const char*)h2 + byte);
    }
#pragma unroll
    for (int ni = 0; ni < 4; ++ni) {
      int c = cBase + ni * 16 + l15;
      b[ni] = *(const bf16x8*)(wm3t + (size_t)c * 128 + k0);
    }
#pragma unroll
    for (int mi = 0; mi < 4; ++mi)
#pragma unroll
      for (int ni = 0; ni < 4; ++ni)
        acc[mi][ni] = __builtin_amdgcn_mfma_f32_16x16x32_bf16(a[mi], b[ni], acc[mi][ni], 0, 0, 0);
  }
#pragma unroll
  for (int mi = 0; mi < 4; ++mi)
#pragma unroll
    for (int ni = 0; ni < 4; ++ni) {
      int c = cBase + ni * 16 + l15;
      float bias = mb3[c];
#pragma unroll
      for (int j = 0; j < 4; ++j) {
        int r = rBase + mi * 16 + rj + j;
        if (r < rMax) {
          int nid = rIds[r];
          unsafeAtomicAdd(inbox + (size_t)nid * FEAT + c, acc[mi][ni][j] + bias);
        }
      }
    }
}

// ---------------- node kernel: out = nodes + MLP([nodes|inbox]) ----------------
// block: 512 thr = 8 waves as 4(M)x2(N); 256 nodes x 128 cols
__global__ __launch_bounds__(512) void node_kernel(const float* __restrict__ nodes,
                                                   const float* __restrict__ inbox,
                                                   const bf16* __restrict__ wn1t,
                                                   const bf16* __restrict__ wn2t,
                                                   const bf16* __restrict__ wn3t,
                                                   const float* __restrict__ nb1,
                                                   const float* __restrict__ nb2,
                                                   const float* __restrict__ nb3,
                                                   float* __restrict__ out) {
  __shared__ bf16 h1[256 * 128];
  __shared__ bf16 h2[256 * 128];
  const int tid = threadIdx.x;
  const int lane = tid & 63, wid = tid >> 6;
  const int wm = wid >> 1, wn = wid & 1;
  const int rBase = wm * 64, cBase = wn * 64;
  const int l15 = lane & 15, ka = (lane >> 4) * 8, rj = (lane >> 4) * 4;
  const int nBase = blockIdx.x * 256;

  f32x4 acc[4][4];
  // ---- layer 1: K=256 over [nodes | inbox], f32->bf16 inline ----
#pragma unroll
  for (int mi = 0; mi < 4; ++mi)
#pragma unroll
    for (int ni = 0; ni < 4; ++ni) acc[mi][ni] = (f32x4){0.f, 0.f, 0.f, 0.f};
#pragma unroll
  for (int kk = 0; kk < 8; ++kk) {
    const int k0 = kk * 32 + ka;
    bf16x8 a[4], b[4];
#pragma unroll
    for (int mi = 0; mi < 4; ++mi) {
      int n = nBase + rBase + mi * 16 + l15;
      if (n > N_NODES - 1) n = N_NODES - 1;
      const float* src = (kk < 4) ? (nodes + (size_t)n * FEAT + k0)
                                  : (inbox + (size_t)n * FEAT + (k0 - 128));
      a[mi] = cvt_f32x8_bf16(src);
    }
#pragma unroll
    for (int ni = 0; ni < 4; ++ni) {
      int c = cBase + ni * 16 + l15;
      b[ni] = *(const bf16x8*)(wn1t + (size_t)c * 256 + k0);
    }
#pragma unroll
    for (int mi = 0; mi < 4; ++mi)
#pragma unroll
      for (int ni = 0; ni < 4; ++ni)
        acc[mi][ni] = __builtin_amdgcn_mfma_f32_16x16x32_bf16(a[mi], b[ni], acc[mi][ni], 0, 0, 0);
  }
#pragma unroll
  for (int mi = 0; mi < 4; ++mi)
#pragma unroll
    for (int ni = 0; ni < 4; ++ni) {
      int c = cBase + ni * 16 + l15;
      float bias = nb1[c];
#pragma unroll
      for (int j = 0; j < 4; ++j) {
        int r = rBase + mi * 16 + rj + j;
        float v = acc[mi][ni][j] + bias;
        v = v > 0.f ? v : 0.f;
        int byte = r * 256 + ((c * 2) ^ ((r & 7) << 4));
        *(bf16*)((char*)h1 + byte) = (bf16)v;
      }
    }
  __syncthreads();

  // ---- layer 2 ----
#pragma unroll
  for (int mi = 0; mi < 4; ++mi)
#pragma unroll
    for (int ni = 0; ni < 4; ++ni) acc[mi][ni] = (f32x4){0.f, 0.f, 0.f, 0.f};
#pragma unroll
  for (int kk = 0; kk < 4; ++kk) {
    const int k0 = kk * 32 + ka;
    bf16x8 a[4], b[4];
#pragma unroll
    for (int mi = 0; mi < 4; ++mi) {
      int r = rBase + mi * 16 + l15;
      int byte = r * 256 + ((k0 * 2) ^ ((r & 7) << 4));
      a[mi] = *(const bf16x8*)((const char*)h1 + byte);
    }
#pragma unroll
    for (int ni = 0; ni < 4; ++ni) {
      int c = cBase + ni * 16 + l15;
      b[ni] = *(const bf16x8*)(wn2t + (size_t)c * 128 + k0);
    }
#pragma unroll
    for (int mi = 0; mi < 4; ++mi)
#pragma unroll
      for (int ni = 0; ni < 4; ++ni)
        acc[mi][ni] = __builtin_amdgcn_mfma_f32_16x16x32_bf16(a[mi], b[ni], acc[mi][ni], 0, 0, 0);
  }
#pragma unroll
  for (int mi = 0; mi < 4; ++mi)
#pragma unroll
    for (int ni = 0; ni < 4; ++ni) {
      int c = cBase + ni * 16 + l15;
      float bias = nb2[c];
#pragma unroll
      for (int j = 0; j < 4; ++j) {
        int r = rBase + mi * 16 + rj + j;
        float v = acc[mi][ni][j] + bias;
        v = v > 0.f ? v : 0.f;
        int byte = r * 256 + ((c * 2) ^ ((r & 7) << 4));
        *(bf16*)((char*)h2 + byte) = (bf16)v;
      }
    }
  __syncthreads();

  // ---- layer 3 + residual store ----
#pragma unroll
  for (int mi = 0; mi < 4; ++mi)
#pragma unroll
    for (int ni = 0; ni < 4; ++ni) acc[mi][ni] = (f32x4){0.f, 0.f, 0.f, 0.f};
#pragma unroll
  for (int kk = 0; kk < 4; ++kk) {
    const int k0 = kk * 32 + ka;
    bf16x8 a[4], b[4];
#pragma unroll
    for (int mi = 0; mi < 4; ++mi) {
      int r = rBase + mi * 16 + l15;
      int byte = r * 256 + ((k0 * 2) ^ ((r & 7) << 4));
      a[mi] = *(const bf16x8*)((const char*)h2 + byte);
    }
#pragma unroll
    for (int ni = 0; ni < 4; ++ni) {
      int c = cBase + ni * 16 + l15;
      b[ni] = *(const bf16x8*)(wn3t + (size_t)c * 128 + k0);
    }
#pragma unroll
    for (int mi = 0; mi < 4; ++mi)
#pragma unroll
      for (int ni = 0; ni < 4; ++ni)
        acc[mi][ni] = __builtin_amdgcn_mfma_f32_16x16x32_bf16(a[mi], b[ni], acc[mi][ni], 0, 0, 0);
  }
#pragma unroll
  for (int mi = 0; mi < 4; ++mi)
#pragma unroll
    for (int ni = 0; ni < 4; ++ni) {
      int c = cBase + ni * 16 + l15;
      float bias = nb3[c];
#pragma unroll
      for (int j = 0; j < 4; ++j) {
        int r = rBase + mi * 16 + rj + j;
        int n = nBase + r;
        if (n < N_NODES)
          out[(size_t)n * FEAT + c] = nodes[(size_t)n * FEAT + c] + acc[mi][ni][j] + bias;
      }
    }
}

extern "C" void kernel_launch(void* const* d_in, const int* in_sizes, int n_in,
                              void* d_out, int out_size, void* d_ws, size_t ws_size,
                              hipStream_t stream) {
  const float* nodes = (const float*)d_in[0];
  const int* senders = (const int*)d_in[1];
  const int* receivers = (const int*)d_in[2];
  const float* mw1 = (const float*)d_in[3];
  const float* mb1 = (const float*)d_in[4];
  const float* mw2 = (const float*)d_in[5];
  const float* mb2 = (const float*)d_in[6];
  const float* mw3 = (const float*)d_in[7];
  const float* mb3 = (const float*)d_in[8];
  const float* nw1 = (const float*)d_in[9];
  const float* nb1 = (const float*)d_in[10];
  const float* nw2 = (const float*)d_in[11];
  const float* nb2 = (const float*)d_in[12];
  const float* nw3 = (const float*)d_in[13];
  const float* nb3 = (const float*)d_in[14];
  float* out = (float*)d_out;
  const int E = in_sizes[1];

  char* ws = (char*)d_ws;
  float* inbox = (float*)(ws);
  bf16* uv = (bf16*)(ws + INBOX_BYTES);
  bf16* w = (bf16*)(ws + INBOX_BYTES + UV_BYTES);

  hipMemsetAsync(inbox, 0, INBOX_BYTES, stream);
  prep_weights_kernel<<<(W_TOTAL + 255) / 256, 256, 0, stream>>>(mw1, mw2, mw3, nw1, nw2, nw3, w);
  uv_gemm_kernel<<<(N_NODES + 127) / 128, 512, 0, stream>>>(nodes, w + WUV_OFF, mb1, uv);
  edge_kernel<<<(E + 255) / 256, 512, 0, stream>>>(uv, senders, receivers, w + WM2_OFF,
                                                   w + WM3_OFF, mb2, mb3, inbox, E);
  node_kernel<<<(N_NODES + 255) / 256, 512, 0, stream>>>(nodes, inbox, w + WN1_OFF, w + WN2_OFF,
                                                         w + WN3_OFF, nb1, nb2, nb3, out);
}

// Round 3
// 533.005 us; speedup vs baseline: 1.0117x; 1.0117x over previous
//
#include <hip/hip_runtime.h>
#include <hip/hip_bf16.h>
#include <stdint.h>

typedef __bf16 bf16;
typedef bf16 bf16x8 __attribute__((ext_vector_type(8)));
typedef float f32x4 __attribute__((ext_vector_type(4)));

#define N_NODES 50000
#define FEAT 128

static constexpr size_t INBOX_BYTES = (size_t)N_NODES * FEAT * 4;   // 25.6 MB f32 inbox
static constexpr size_t UV_BYTES    = (size_t)N_NODES * 256 * 2;    // 25.6 MB bf16 uv

// weight table element offsets (bf16 elements) within ws weight region
#define WUV_OFF 0        // [256][128]  combined (mw1 top|bottom) transposed
#define WM2_OFF 32768    // [128][128]
#define WM3_OFF 49152    // [128][128]
#define WN1_OFF 65536    // [128][256]
#define WN2_OFF 98304    // [128][128]
#define WN3_OFF 114688   // [128][128]
#define W_TOTAL 131072

__device__ __forceinline__ bf16x8 cvt_f32x8_bf16(const float* __restrict__ p) {
  float4 f0 = *(const float4*)p;
  float4 f1 = *(const float4*)(p + 4);
  bf16x8 t;
  t[0] = (bf16)f0.x; t[1] = (bf16)f0.y; t[2] = (bf16)f0.z; t[3] = (bf16)f0.w;
  t[4] = (bf16)f1.x; t[5] = (bf16)f1.y; t[6] = (bf16)f1.z; t[7] = (bf16)f1.w;
  return t;
}

// ---------------- prep: cast+transpose weights to bf16 ----------------
__global__ void prep_weights_kernel(const float* __restrict__ mw1, const float* __restrict__ mw2,
                                    const float* __restrict__ mw3, const float* __restrict__ nw1,
                                    const float* __restrict__ nw2, const float* __restrict__ nw3,
                                    bf16* __restrict__ w) {
  int i = blockIdx.x * blockDim.x + threadIdx.x;
  if (i >= W_TOTAL) return;
  float v;
  if (i < WM2_OFF) {            // wuv_t[c][k], c in [0,256), k in [0,128)
    int c = i >> 7, k = i & 127;
    v = (c < 128) ? mw1[k * 128 + c] : mw1[(128 + k) * 128 + (c - 128)];
  } else if (i < WM3_OFF) {     // wm2_t[c][k]
    int j = i - WM2_OFF; int c = j >> 7, k = j & 127;
    v = mw2[k * 128 + c];
  } else if (i < WN1_OFF) {     // wm3_t[c][k]
    int j = i - WM3_OFF; int c = j >> 7, k = j & 127;
    v = mw3[k * 128 + c];
  } else if (i < WN2_OFF) {     // wn1_t[c][k], k in [0,256)
    int j = i - WN1_OFF; int c = j >> 8, k = j & 255;
    v = nw1[k * 128 + c];
  } else if (i < WN3_OFF) {     // wn2_t[c][k]
    int j = i - WN2_OFF; int c = j >> 7, k = j & 127;
    v = nw2[k * 128 + c];
  } else {                      // wn3_t[c][k]
    int j = i - WN3_OFF; int c = j >> 7, k = j & 127;
    v = nw3[k * 128 + c];
  }
  w[i] = (bf16)v;
}

// ---------------- uv = nodes @ [W1a | W1b] (+b1 on u-half), bf16 out ----------------
__global__ __launch_bounds__(512) void uv_gemm_kernel(const float* __restrict__ nodes,
                                                      const bf16* __restrict__ wuvt,
                                                      const float* __restrict__ mb1,
                                                      bf16* __restrict__ uv) {
  const int tid = threadIdx.x;
  const int lane = tid & 63, wid = tid >> 6;
  const int wm = wid >> 2, wn = wid & 3;
  const int rBase = blockIdx.x * 128 + wm * 64;
  const int cBase = wn * 64;
  const int l15 = lane & 15, ka = (lane >> 4) * 8, rj = (lane >> 4) * 4;

  f32x4 acc[4][4];
#pragma unroll
  for (int mi = 0; mi < 4; ++mi)
#pragma unroll
    for (int ni = 0; ni < 4; ++ni) acc[mi][ni] = (f32x4){0.f, 0.f, 0.f, 0.f};

#pragma unroll
  for (int kk = 0; kk < 4; ++kk) {
    const int k0 = kk * 32 + ka;
    bf16x8 a[4], b[4];
#pragma unroll
    for (int mi = 0; mi < 4; ++mi) {
      int r = rBase + mi * 16 + l15;
      if (r > N_NODES - 1) r = N_NODES - 1;
      a[mi] = cvt_f32x8_bf16(nodes + (size_t)r * FEAT + k0);
    }
#pragma unroll
    for (int ni = 0; ni < 4; ++ni) {
      int c = cBase + ni * 16 + l15;
      b[ni] = *(const bf16x8*)(wuvt + (size_t)c * 128 + k0);
    }
#pragma unroll
    for (int mi = 0; mi < 4; ++mi)
#pragma unroll
      for (int ni = 0; ni < 4; ++ni)
        acc[mi][ni] = __builtin_amdgcn_mfma_f32_16x16x32_bf16(a[mi], b[ni], acc[mi][ni], 0, 0, 0);
  }
#pragma unroll
  for (int mi = 0; mi < 4; ++mi)
#pragma unroll
    for (int ni = 0; ni < 4; ++ni) {
      int c = cBase + ni * 16 + l15;
      float bias = (c < FEAT) ? mb1[c] : 0.f;  // fold b1 into u-half
#pragma unroll
      for (int j = 0; j < 4; ++j) {
        int r = rBase + mi * 16 + rj + j;
        if (r < N_NODES) uv[(size_t)r * 256 + c] = (bf16)(acc[mi][ni][j] + bias);
      }
    }
}

// ---------------- edge kernel v2: barrier-free waves, 32 edges/wave ----------------
// block: 256 thr = 4 waves; each wave owns 32 edges end-to-end.
// layer2 A = relu(u[recv]+v[send]) straight from global; layer2->layer3 transpose
// via private 8KB XOR-swizzled LDS slice; scatter via f32 atomics.
#define EB 128
__global__ __launch_bounds__(256, 3) void edge_kernel(const bf16* __restrict__ uv,
                                                      const int* __restrict__ senders,
                                                      const int* __restrict__ receivers,
                                                      const bf16* __restrict__ wm2t,
                                                      const bf16* __restrict__ wm3t,
                                                      const float* __restrict__ mb2,
                                                      const float* __restrict__ mb3,
                                                      float* __restrict__ inbox, int E) {
  __shared__ int rIds[EB];
  __shared__ int sIds[EB];
  __shared__ bf16 hbuf[4][32 * 128];  // 8KB per-wave transpose slice

  const int tid = threadIdx.x;
  const int e0 = blockIdx.x * EB;
  const int rMax = (E - e0 < EB) ? (E - e0) : EB;

  if (tid < EB) {
    int e = e0 + tid; if (e >= E) e = E - 1;
    rIds[tid] = receivers[e];
  } else {
    int t = tid - EB;
    int e = e0 + t; if (e >= E) e = E - 1;
    sIds[t] = senders[e];
  }
  __syncthreads();

  const int lane = tid & 63, wid = tid >> 6;
  const int l15 = lane & 15, ka = (lane >> 4) * 8, rj = (lane >> 4) * 4;
  const int rW = wid * 32;            // wave's first edge row within block
  bf16* hw = hbuf[wid];

  // ---- gather A-fragments: afr[mi][kk] = relu(u[recv] + v[send]) ----
  bf16x8 afr[2][4];
#pragma unroll
  for (int mi = 0; mi < 2; ++mi) {
    int row = rW + mi * 16 + l15;
    int recv = rIds[row], send = sIds[row];
    const bf16* up = uv + (size_t)recv * 256;
    const bf16* vp = uv + (size_t)send * 256 + 128;
#pragma unroll
    for (int kk = 0; kk < 4; ++kk) {
      int k0 = kk * 32 + ka;
      bf16x8 u8 = *(const bf16x8*)(up + k0);
      bf16x8 v8 = *(const bf16x8*)(vp + k0);
      bf16x8 h;
#pragma unroll
      for (int t = 0; t < 8; ++t) {
        float x = (float)u8[t] + (float)v8[t];
        h[t] = (bf16)(x > 0.f ? x : 0.f);
      }
      afr[mi][kk] = h;
    }
  }

  // ---- layer 2: acc[2][8] = h1 @ W2 (M=32, N=128, K=128) ----
  f32x4 acc[2][8];
#pragma unroll
  for (int mi = 0; mi < 2; ++mi)
#pragma unroll
    for (int ni = 0; ni < 8; ++ni) acc[mi][ni] = (f32x4){0.f, 0.f, 0.f, 0.f};
#pragma unroll
  for (int kk = 0; kk < 4; ++kk) {
    const int k0 = kk * 32 + ka;
    bf16x8 b[8];
#pragma unroll
    for (int ni = 0; ni < 8; ++ni) {
      int c = ni * 16 + l15;
      b[ni] = *(const bf16x8*)(wm2t + (size_t)c * 128 + k0);
    }
#pragma unroll
    for (int mi = 0; mi < 2; ++mi)
#pragma unroll
      for (int ni = 0; ni < 8; ++ni)
        acc[mi][ni] = __builtin_amdgcn_mfma_f32_16x16x32_bf16(afr[mi][kk], b[ni], acc[mi][ni], 0, 0, 0);
  }

  // ---- epilogue layer2: relu+bias -> bf16 -> wave-private swizzled LDS ----
#pragma unroll
  for (int mi = 0; mi < 2; ++mi)
#pragma unroll
    for (int ni = 0; ni < 8; ++ni) {
      int c = ni * 16 + l15;
      float bias = mb2[c];
#pragma unroll
      for (int j = 0; j < 4; ++j) {
        int row = mi * 16 + rj + j;  // 0..31 within wave tile
        float v = acc[mi][ni][j] + bias;
        v = v > 0.f ? v : 0.f;
        int byte = row * 256 + ((c * 2) ^ ((row & 7) << 4));
        *(bf16*)((char*)hw + byte) = (bf16)v;
      }
    }
  // wave-private slice: enforce LDS write->read ordering without __syncthreads
  asm volatile("s_waitcnt lgkmcnt(0)" ::: "memory");
  __builtin_amdgcn_sched_barrier(0);

  // ---- layer 3: acc3[2][8] = h2 @ W3 ----
  bf16x8 a3[2][4];
#pragma unroll
  for (int mi = 0; mi < 2; ++mi) {
    int row = mi * 16 + l15;
#pragma unroll
    for (int kk = 0; kk < 4; ++kk) {
      int k0 = kk * 32 + ka;
      int byte = row * 256 + ((k0 * 2) ^ ((row & 7) << 4));
      a3[mi][kk] = *(const bf16x8*)((const char*)hw + byte);
    }
  }
  f32x4 acc3[2][8];
#pragma unroll
  for (int mi = 0; mi < 2; ++mi)
#pragma unroll
    for (int ni = 0; ni < 8; ++ni) acc3[mi][ni] = (f32x4){0.f, 0.f, 0.f, 0.f};
#pragma unroll
  for (int kk = 0; kk < 4; ++kk) {
    const int k0 = kk * 32 + ka;
    bf16x8 b[8];
#pragma unroll
    for (int ni = 0; ni < 8; ++ni) {
      int c = ni * 16 + l15;
      b[ni] = *(const bf16x8*)(wm3t + (size_t)c * 128 + k0);
    }
#pragma unroll
    for (int mi = 0; mi < 2; ++mi)
#pragma unroll
      for (int ni = 0; ni < 8; ++ni)
        acc3[mi][ni] = __builtin_amdgcn_mfma_f32_16x16x32_bf16(a3[mi][kk], b[ni], acc3[mi][ni], 0, 0, 0);
  }

  // ---- f32 atomic scatter ----
#pragma unroll
  for (int mi = 0; mi < 2; ++mi)
#pragma unroll
    for (int ni = 0; ni < 8; ++ni) {
      int c = ni * 16 + l15;
      float bias = mb3[c];
#pragma unroll
      for (int j = 0; j < 4; ++j) {
        int row = rW + mi * 16 + rj + j;
        if (row < rMax)
          unsafeAtomicAdd(inbox + (size_t)rIds[row] * FEAT + c, acc3[mi][ni][j] + bias);
      }
    }
}

// ---------------- node kernel: out = nodes + MLP([nodes|inbox]) ----------------
__global__ __launch_bounds__(512) void node_kernel(const float* __restrict__ nodes,
                                                   const float* __restrict__ inbox,
                                                   const bf16* __restrict__ wn1t,
                                                   const bf16* __restrict__ wn2t,
                                                   const bf16* __restrict__ wn3t,
                                                   const float* __restrict__ nb1,
                                                   const float* __restrict__ nb2,
                                                   const float* __restrict__ nb3,
                                                   float* __restrict__ out) {
  __shared__ bf16 h1[256 * 128];
  __shared__ bf16 h2[256 * 128];
  const int tid = threadIdx.x;
  const int lane = tid & 63, wid = tid >> 6;
  const int wm = wid >> 1, wn = wid & 1;
  const int rBase = wm * 64, cBase = wn * 64;
  const int l15 = lane & 15, ka = (lane >> 4) * 8, rj = (lane >> 4) * 4;
  const int nBase = blockIdx.x * 256;

  f32x4 acc[4][4];
#pragma unroll
  for (int mi = 0; mi < 4; ++mi)
#pragma unroll
    for (int ni = 0; ni < 4; ++ni) acc[mi][ni] = (f32x4){0.f, 0.f, 0.f, 0.f};
#pragma unroll
  for (int kk = 0; kk < 8; ++kk) {
    const int k0 = kk * 32 + ka;
    bf16x8 a[4], b[4];
#pragma unroll
    for (int mi = 0; mi < 4; ++mi) {
      int n = nBase + rBase + mi * 16 + l15;
      if (n > N_NODES - 1) n = N_NODES - 1;
      const float* src = (kk < 4) ? (nodes + (size_t)n * FEAT + k0)
                                  : (inbox + (size_t)n * FEAT + (k0 - 128));
      a[mi] = cvt_f32x8_bf16(src);
    }
#pragma unroll
    for (int ni = 0; ni < 4; ++ni) {
      int c = cBase + ni * 16 + l15;
      b[ni] = *(const bf16x8*)(wn1t + (size_t)c * 256 + k0);
    }
#pragma unroll
    for (int mi = 0; mi < 4; ++mi)
#pragma unroll
      for (int ni = 0; ni < 4; ++ni)
        acc[mi][ni] = __builtin_amdgcn_mfma_f32_16x16x32_bf16(a[mi], b[ni], acc[mi][ni], 0, 0, 0);
  }
#pragma unroll
  for (int mi = 0; mi < 4; ++mi)
#pragma unroll
    for (int ni = 0; ni < 4; ++ni) {
      int c = cBase + ni * 16 + l15;
      float bias = nb1[c];
#pragma unroll
      for (int j = 0; j < 4; ++j) {
        int r = rBase + mi * 16 + rj + j;
        float v = acc[mi][ni][j] + bias;
        v = v > 0.f ? v : 0.f;
        int byte = r * 256 + ((c * 2) ^ ((r & 7) << 4));
        *(bf16*)((char*)h1 + byte) = (bf16)v;
      }
    }
  __syncthreads();

#pragma unroll
  for (int mi = 0; mi < 4; ++mi)
#pragma unroll
    for (int ni = 0; ni < 4; ++ni) acc[mi][ni] = (f32x4){0.f, 0.f, 0.f, 0.f};
#pragma unroll
  for (int kk = 0; kk < 4; ++kk) {
    const int k0 = kk * 32 + ka;
    bf16x8 a[4], b[4];
#pragma unroll
    for (int mi = 0; mi < 4; ++mi) {
      int r = rBase + mi * 16 + l15;
      int byte = r * 256 + ((k0 * 2) ^ ((r & 7) << 4));
      a[mi] = *(const bf16x8*)((const char*)h1 + byte);
    }
#pragma unroll
    for (int ni = 0; ni < 4; ++ni) {
      int c = cBase + ni * 16 + l15;
      b[ni] = *(const bf16x8*)(wn2t + (size_t)c * 128 + k0);
    }
#pragma unroll
    for (int mi = 0; mi < 4; ++mi)
#pragma unroll
      for (int ni = 0; ni < 4; ++ni)
        acc[mi][ni] = __builtin_amdgcn_mfma_f32_16x16x32_bf16(a[mi], b[ni], acc[mi][ni], 0, 0, 0);
  }
#pragma unroll
  for (int mi = 0; mi < 4; ++mi)
#pragma unroll
    for (int ni = 0; ni < 4; ++ni) {
      int c = cBase + ni * 16 + l15;
      float bias = nb2[c];
#pragma unroll
      for (int j = 0; j < 4; ++j) {
        int r = rBase + mi * 16 + rj + j;
        float v = acc[mi][ni][j] + bias;
        v = v > 0.f ? v : 0.f;
        int byte = r * 256 + ((c * 2) ^ ((r & 7) << 4));
        *(bf16*)((char*)h2 + byte) = (bf16)v;
      }
    }
  __syncthreads();

#pragma unroll
  for (int mi = 0; mi < 4; ++mi)
#pragma unroll
    for (int ni = 0; ni < 4; ++ni) acc[mi][ni] = (f32x4){0.f, 0.f, 0.f, 0.f};
#pragma unroll
  for (int kk = 0; kk < 4; ++kk) {
    const int k0 = kk * 32 + ka;
    bf16x8 a[4], b[4];
#pragma unroll
    for (int mi = 0; mi < 4; ++mi) {
      int r = rBase + mi * 16 + l15;
      int byte = r * 256 + ((k0 * 2) ^ ((r & 7) << 4));
      a[mi] = *(const bf16x8*)((const char*)h2 + byte);
    }
#pragma unroll
    for (int ni = 0; ni < 4; ++ni) {
      int c = cBase + ni * 16 + l15;
      b[ni] = *(const bf16x8*)(wn3t + (size_t)c * 128 + k0);
    }
#pragma unroll
    for (int mi = 0; mi < 4; ++mi)
#pragma unroll
      for (int ni = 0; ni < 4; ++ni)
        acc[mi][ni] = __builtin_amdgcn_mfma_f32_16x16x32_bf16(a[mi], b[ni], acc[mi][ni], 0, 0, 0);
  }
#pragma unroll
  for (int mi = 0; mi < 4; ++mi)
#pragma unroll
    for (int ni = 0; ni < 4; ++ni) {
      int c = cBase + ni * 16 + l15;
      float bias = nb3[c];
#pragma unroll
      for (int j = 0; j < 4; ++j) {
        int r = rBase + mi * 16 + rj + j;
        int n = nBase + r;
        if (n < N_NODES)
          out[(size_t)n * FEAT + c] = nodes[(size_t)n * FEAT + c] + acc[mi][ni][j] + bias;
      }
    }
}

extern "C" void kernel_launch(void* const* d_in, const int* in_sizes, int n_in,
                              void* d_out, int out_size, void* d_ws, size_t ws_size,
                              hipStream_t stream) {
  const float* nodes = (const float*)d_in[0];
  const int* senders = (const int*)d_in[1];
  const int* receivers = (const int*)d_in[2];
  const float* mw1 = (const float*)d_in[3];
  const float* mb1 = (const float*)d_in[4];
  const float* mw2 = (const float*)d_in[5];
  const float* mb2 = (const float*)d_in[6];
  const float* mw3 = (const float*)d_in[7];
  const float* mb3 = (const float*)d_in[8];
  const float* nw1 = (const float*)d_in[9];
  const float* nb1 = (const float*)d_in[10];
  const float* nw2 = (const float*)d_in[11];
  const float* nb2 = (const float*)d_in[12];
  const float* nw3 = (const float*)d_in[13];
  const float* nb3 = (const float*)d_in[14];
  float* out = (float*)d_out;
  const int E = in_sizes[1];

  char* ws = (char*)d_ws;
  float* inbox = (float*)(ws);
  bf16* uv = (bf16*)(ws + INBOX_BYTES);
  bf16* w = (bf16*)(ws + INBOX_BYTES + UV_BYTES);

  hipMemsetAsync(inbox, 0, INBOX_BYTES, stream);
  prep_weights_kernel<<<(W_TOTAL + 255) / 256, 256, 0, stream>>>(mw1, mw2, mw3, nw1, nw2, nw3, w);
  uv_gemm_kernel<<<(N_NODES + 127) / 128, 512, 0, stream>>>(nodes, w + WUV_OFF, mb1, uv);
  edge_kernel<<<(E + EB - 1) / EB, 256, 0, stream>>>(uv, senders, receivers, w + WM2_OFF,
                                                     w + WM3_OFF, mb2, mb3, inbox, E);
  node_kernel<<<(N_NODES + 255) / 256, 512, 0, stream>>>(nodes, inbox, w + WN1_OFF, w + WN2_OFF,
                                                         w + WN3_OFF, nb1, nb2, nb3, out);
}

// Round 4
// 501.720 us; speedup vs baseline: 1.0748x; 1.0624x over previous
//
#include <hip/hip_runtime.h>
#include <hip/hip_bf16.h>
#include <stdint.h>

typedef __bf16 bf16;
typedef bf16 bf16x8 __attribute__((ext_vector_type(8)));
typedef float f32x4 __attribute__((ext_vector_type(4)));

#define N_NODES 50000
#define FEAT 128
#define NB_SCAN ((N_NODES + 1023) / 1024)   // 49

static constexpr size_t UV_BYTES    = (size_t)N_NODES * 256 * 2;    // 25.6 MB bf16 uv
static constexpr size_t INBOX_BYTES = (size_t)N_NODES * FEAT * 4;   // 25.6 MB f32 inbox

#define WUV_OFF 0        // [256][128]  combined (mw1 top|bottom) transposed
#define WM2_OFF 32768    // [128][128]
#define WM3_OFF 49152    // [128][128]
#define WN1_OFF 65536    // [128][256]
#define WN2_OFF 98304    // [128][128]
#define WN3_OFF 114688   // [128][128]
#define W_TOTAL 131072
static constexpr size_t W_BYTES = (size_t)W_TOTAL * 2;

__device__ __forceinline__ bf16x8 cvt_f32x8_bf16(const float* __restrict__ p) {
  float4 f0 = *(const float4*)p;
  float4 f1 = *(const float4*)(p + 4);
  bf16x8 t;
  t[0] = (bf16)f0.x; t[1] = (bf16)f0.y; t[2] = (bf16)f0.z; t[3] = (bf16)f0.w;
  t[4] = (bf16)f1.x; t[5] = (bf16)f1.y; t[6] = (bf16)f1.z; t[7] = (bf16)f1.w;
  return t;
}

// ---------------- prep: cast+transpose weights to bf16 ----------------
__global__ void prep_weights_kernel(const float* __restrict__ mw1, const float* __restrict__ mw2,
                                    const float* __restrict__ mw3, const float* __restrict__ nw1,
                                    const float* __restrict__ nw2, const float* __restrict__ nw3,
                                    bf16* __restrict__ w) {
  int i = blockIdx.x * blockDim.x + threadIdx.x;
  if (i >= W_TOTAL) return;
  float v;
  if (i < WM2_OFF) {
    int c = i >> 7, k = i & 127;
    v = (c < 128) ? mw1[k * 128 + c] : mw1[(128 + k) * 128 + (c - 128)];
  } else if (i < WM3_OFF) {
    int j = i - WM2_OFF; int c = j >> 7, k = j & 127;
    v = mw2[k * 128 + c];
  } else if (i < WN1_OFF) {
    int j = i - WM3_OFF; int c = j >> 7, k = j & 127;
    v = mw3[k * 128 + c];
  } else if (i < WN2_OFF) {
    int j = i - WN1_OFF; int c = j >> 8, k = j & 255;
    v = nw1[k * 128 + c];
  } else if (i < WN3_OFF) {
    int j = i - WN2_OFF; int c = j >> 7, k = j & 127;
    v = nw2[k * 128 + c];
  } else {
    int j = i - WN3_OFF; int c = j >> 7, k = j & 127;
    v = nw3[k * 128 + c];
  }
  w[i] = (bf16)v;
}

// ---------------- CSR build ----------------
__global__ void hist_kernel(const int* __restrict__ receivers, int* __restrict__ cnt, int E) {
  int i = blockIdx.x * blockDim.x + threadIdx.x;
  if (i < E) atomicAdd(&cnt[receivers[i]], 1);
}

__global__ __launch_bounds__(1024) void scan1_kernel(const int* __restrict__ cnt,
                                                     int* __restrict__ offs,
                                                     int* __restrict__ bsum) {
  __shared__ int s[1024];
  const int tid = threadIdx.x;
  const int g = blockIdx.x * 1024 + tid;
  int x = (g < N_NODES) ? cnt[g] : 0;
  s[tid] = x;
  __syncthreads();
  for (int off = 1; off < 1024; off <<= 1) {
    int v = (tid >= off) ? s[tid - off] : 0;
    __syncthreads();
    s[tid] += v;
    __syncthreads();
  }
  if (g < N_NODES) offs[g] = s[tid] - x;
  if (tid == 1023) bsum[blockIdx.x] = s[tid];
}

__global__ void scan2_kernel(int* __restrict__ bsum) {  // 1 block x 64
  __shared__ int s[64];
  const int tid = threadIdx.x;
  int x = (tid < NB_SCAN) ? bsum[tid] : 0;
  s[tid] = x;
  __syncthreads();
  for (int off = 1; off < 64; off <<= 1) {
    int v = (tid >= off) ? s[tid - off] : 0;
    __syncthreads();
    s[tid] += v;
    __syncthreads();
  }
  if (tid < NB_SCAN) bsum[tid] = s[tid] - x;
}

__global__ __launch_bounds__(1024) void scan3_kernel(int* __restrict__ offs,
                                                     const int* __restrict__ bsum, int E) {
  const int tid = threadIdx.x;
  const int g = blockIdx.x * 1024 + tid;
  if (g < N_NODES) offs[g] += bsum[blockIdx.x];
  if (blockIdx.x == 0 && tid == 0) offs[N_NODES] = E;
}

__global__ void pos_kernel(const int* __restrict__ receivers, const int* __restrict__ offs,
                           int* __restrict__ cur, int* __restrict__ pos, int E) {
  int i = blockIdx.x * blockDim.x + threadIdx.x;
  if (i < E) {
    int r = receivers[i];
    pos[i] = offs[r] + atomicAdd(&cur[r], 1);
  }
}

// ---------------- uv = nodes @ [W1a | W1b] (+b1 on u-half), bf16 out ----------------
__global__ __launch_bounds__(512) void uv_gemm_kernel(const float* __restrict__ nodes,
                                                      const bf16* __restrict__ wuvt,
                                                      const float* __restrict__ mb1,
                                                      bf16* __restrict__ uv) {
  const int tid = threadIdx.x;
  const int lane = tid & 63, wid = tid >> 6;
  const int wm = wid >> 2, wn = wid & 3;
  const int rBase = blockIdx.x * 128 + wm * 64;
  const int cBase = wn * 64;
  const int l15 = lane & 15, ka = (lane >> 4) * 8, rj = (lane >> 4) * 4;

  f32x4 acc[4][4];
#pragma unroll
  for (int mi = 0; mi < 4; ++mi)
#pragma unroll
    for (int ni = 0; ni < 4; ++ni) acc[mi][ni] = (f32x4){0.f, 0.f, 0.f, 0.f};

#pragma unroll
  for (int kk = 0; kk < 4; ++kk) {
    const int k0 = kk * 32 + ka;
    bf16x8 a[4], b[4];
#pragma unroll
    for (int mi = 0; mi < 4; ++mi) {
      int r = rBase + mi * 16 + l15;
      if (r > N_NODES - 1) r = N_NODES - 1;
      a[mi] = cvt_f32x8_bf16(nodes + (size_t)r * FEAT + k0);
    }
#pragma unroll
    for (int ni = 0; ni < 4; ++ni) {
      int c = cBase + ni * 16 + l15;
      b[ni] = *(const bf16x8*)(wuvt + (size_t)c * 128 + k0);
    }
#pragma unroll
    for (int mi = 0; mi < 4; ++mi)
#pragma unroll
      for (int ni = 0; ni < 4; ++ni)
        acc[mi][ni] = __builtin_amdgcn_mfma_f32_16x16x32_bf16(a[mi], b[ni], acc[mi][ni], 0, 0, 0);
  }
#pragma unroll
  for (int mi = 0; mi < 4; ++mi)
#pragma unroll
    for (int ni = 0; ni < 4; ++ni) {
      int c = cBase + ni * 16 + l15;
      float bias = (c < FEAT) ? mb1[c] : 0.f;
#pragma unroll
      for (int j = 0; j < 4; ++j) {
        int r = rBase + mi * 16 + rj + j;
        if (r < N_NODES) uv[(size_t)r * 256 + c] = (bf16)(acc[mi][ni][j] + bias);
      }
    }
}

// ---------------- edge kernel ----------------
#define EB 128
template <bool SORT>
__global__ __launch_bounds__(256, 3) void edge_kernel(const bf16* __restrict__ uv,
                                                      const int* __restrict__ senders,
                                                      const int* __restrict__ receivers,
                                                      const int* __restrict__ pos,
                                                      const bf16* __restrict__ wm2t,
                                                      const bf16* __restrict__ wm3t,
                                                      const float* __restrict__ mb2,
                                                      const float* __restrict__ mb3,
                                                      bf16* __restrict__ msg,
                                                      float* __restrict__ inbox, int E) {
  __shared__ int rIds[EB];
  __shared__ int sIds[EB];
  __shared__ int pIds[EB];
  __shared__ bf16 hbuf[4][32 * 128];

  const int tid = threadIdx.x;
  const int e0 = blockIdx.x * EB;
  const int rMax = (E - e0 < EB) ? (E - e0) : EB;

  if (tid < EB) {
    int e = e0 + tid; if (e >= E) e = E - 1;
    rIds[tid] = receivers[e];
    if (SORT) pIds[tid] = pos[e];
  } else {
    int t = tid - EB;
    int e = e0 + t; if (e >= E) e = E - 1;
    sIds[t] = senders[e];
  }
  __syncthreads();

  const int lane = tid & 63, wid = tid >> 6;
  const int l15 = lane & 15, ka = (lane >> 4) * 8, rj = (lane >> 4) * 4;
  const int rW = wid * 32;
  bf16* hw = hbuf[wid];

  bf16x8 afr[2][4];
#pragma unroll
  for (int mi = 0; mi < 2; ++mi) {
    int row = rW + mi * 16 + l15;
    int recv = rIds[row], send = sIds[row];
    const bf16* up = uv + (size_t)recv * 256;
    const bf16* vp = uv + (size_t)send * 256 + 128;
#pragma unroll
    for (int kk = 0; kk < 4; ++kk) {
      int k0 = kk * 32 + ka;
      bf16x8 u8 = *(const bf16x8*)(up + k0);
      bf16x8 v8 = *(const bf16x8*)(vp + k0);
      bf16x8 h;
#pragma unroll
      for (int t = 0; t < 8; ++t) {
        float x = (float)u8[t] + (float)v8[t];
        h[t] = (bf16)(x > 0.f ? x : 0.f);
      }
      afr[mi][kk] = h;
    }
  }

  f32x4 acc[2][8];
#pragma unroll
  for (int mi = 0; mi < 2; ++mi)
#pragma unroll
    for (int ni = 0; ni < 8; ++ni) acc[mi][ni] = (f32x4){0.f, 0.f, 0.f, 0.f};
#pragma unroll
  for (int kk = 0; kk < 4; ++kk) {
    const int k0 = kk * 32 + ka;
    bf16x8 b[8];
#pragma unroll
    for (int ni = 0; ni < 8; ++ni) {
      int c = ni * 16 + l15;
      b[ni] = *(const bf16x8*)(wm2t + (size_t)c * 128 + k0);
    }
#pragma unroll
    for (int mi = 0; mi < 2; ++mi)
#pragma unroll
      for (int ni = 0; ni < 8; ++ni)
        acc[mi][ni] = __builtin_amdgcn_mfma_f32_16x16x32_bf16(afr[mi][kk], b[ni], acc[mi][ni], 0, 0, 0);
  }

#pragma unroll
  for (int mi = 0; mi < 2; ++mi)
#pragma unroll
    for (int ni = 0; ni < 8; ++ni) {
      int c = ni * 16 + l15;
      float bias = mb2[c];
#pragma unroll
      for (int j = 0; j < 4; ++j) {
        int row = mi * 16 + rj + j;
        float v = acc[mi][ni][j] + bias;
        v = v > 0.f ? v : 0.f;
        int byte = row * 256 + ((c * 2) ^ ((row & 7) << 4));
        *(bf16*)((char*)hw + byte) = (bf16)v;
      }
    }
  asm volatile("s_waitcnt lgkmcnt(0)" ::: "memory");
  __builtin_amdgcn_sched_barrier(0);

  bf16x8 a3[2][4];
#pragma unroll
  for (int mi = 0; mi < 2; ++mi) {
    int row = mi * 16 + l15;
#pragma unroll
    for (int kk = 0; kk < 4; ++kk) {
      int k0 = kk * 32 + ka;
      int byte = row * 256 + ((k0 * 2) ^ ((row & 7) << 4));
      a3[mi][kk] = *(const bf16x8*)((const char*)hw + byte);
    }
  }
  f32x4 acc3[2][8];
#pragma unroll
  for (int mi = 0; mi < 2; ++mi)
#pragma unroll
    for (int ni = 0; ni < 8; ++ni) acc3[mi][ni] = (f32x4){0.f, 0.f, 0.f, 0.f};
#pragma unroll
  for (int kk = 0; kk < 4; ++kk) {
    const int k0 = kk * 32 + ka;
    bf16x8 b[8];
#pragma unroll
    for (int ni = 0; ni < 8; ++ni) {
      int c = ni * 16 + l15;
      b[ni] = *(const bf16x8*)(wm3t + (size_t)c * 128 + k0);
    }
#pragma unroll
    for (int mi = 0; mi < 2; ++mi)
#pragma unroll
      for (int ni = 0; ni < 8; ++ni)
        acc3[mi][ni] = __builtin_amdgcn_mfma_f32_16x16x32_bf16(a3[mi][kk], b[ni], acc3[mi][ni], 0, 0, 0);
  }

  if (SORT) {
    asm volatile("s_waitcnt lgkmcnt(0)" ::: "memory");
    __builtin_amdgcn_sched_barrier(0);
#pragma unroll
    for (int mi = 0; mi < 2; ++mi)
#pragma unroll
      for (int ni = 0; ni < 8; ++ni) {
        int c = ni * 16 + l15;
        float bias = mb3[c];
#pragma unroll
        for (int j = 0; j < 4; ++j) {
          int row = mi * 16 + rj + j;
          int byte = row * 256 + ((c * 2) ^ ((row & 7) << 4));
          *(bf16*)((char*)hw + byte) = (bf16)(acc3[mi][ni][j] + bias);
        }
      }
    asm volatile("s_waitcnt lgkmcnt(0)" ::: "memory");
    __builtin_amdgcn_sched_barrier(0);
#pragma unroll
    for (int it = 0; it < 8; ++it) {
      int idx = it * 64 + lane;
      int row = idx >> 4, ch = idx & 15;
      int byte = row * 256 + ((ch * 16) ^ ((row & 7) << 4));
      bf16x8 m = *(const bf16x8*)((const char*)hw + byte);
      int grow = rW + row;
      if (grow < rMax)
        *(bf16x8*)(msg + (size_t)pIds[grow] * FEAT + ch * 8) = m;
    }
  } else {
#pragma unroll
    for (int mi = 0; mi < 2; ++mi)
#pragma unroll
      for (int ni = 0; ni < 8; ++ni) {
        int c = ni * 16 + l15;
        float bias = mb3[c];
#pragma unroll
        for (int j = 0; j < 4; ++j) {
          int row = rW + mi * 16 + rj + j;
          if (row < rMax)
            unsafeAtomicAdd(inbox + (size_t)rIds[row] * FEAT + c, acc3[mi][ni][j] + bias);
        }
      }
  }
}

// ---------------- reduce: inbox[n] = sum msg rows [offs[n], offs[n+1]) ----------------
__global__ __launch_bounds__(256) void reduce_kernel(const bf16* __restrict__ msg,
                                                     const int* __restrict__ offs,
                                                     float* __restrict__ inbox) {
  const int tid = threadIdx.x;
  const int n = blockIdx.x * 64 + (tid >> 2);
  if (n >= N_NODES) return;
  const int sub = tid & 3;
  const int beg = offs[n], end = offs[n + 1];

  float acc[4][8];
#pragma unroll
  for (int q = 0; q < 4; ++q)
#pragma unroll
    for (int t = 0; t < 8; ++t) acc[q][t] = 0.f;

  for (int j = beg; j < end; ++j) {
    const bf16* row = msg + (size_t)j * FEAT + sub * 32;
#pragma unroll
    for (int q = 0; q < 4; ++q) {
      bf16x8 m = *(const bf16x8*)(row + q * 8);
#pragma unroll
      for (int t = 0; t < 8; ++t) acc[q][t] += (float)m[t];
    }
  }
  float* dst = inbox + (size_t)n * FEAT + sub * 32;
#pragma unroll
  for (int q = 0; q < 4; ++q) {
    float4 v0 = {acc[q][0], acc[q][1], acc[q][2], acc[q][3]};
    float4 v1 = {acc[q][4], acc[q][5], acc[q][6], acc[q][7]};
    *(float4*)(dst + q * 8) = v0;
    *(float4*)(dst + q * 8 + 4) = v1;
  }
}

// ---------------- node kernel: out = nodes + MLP([nodes|inbox]) ----------------
__global__ __launch_bounds__(512) void node_kernel(const float* __restrict__ nodes,
                                                   const float* __restrict__ inbox,
                                                   const bf16* __restrict__ wn1t,
                                                   const bf16* __restrict__ wn2t,
                                                   const bf16* __restrict__ wn3t,
                                                   const float* __restrict__ nb1,
                                                   const float* __restrict__ nb2,
                                                   const float* __restrict__ nb3,
                                                   float* __restrict__ out) {
  __shared__ bf16 h1[256 * 128];
  __shared__ bf16 h2[256 * 128];
  const int tid = threadIdx.x;
  const int lane = tid & 63, wid = tid >> 6;
  const int wm = wid >> 1, wn = wid & 1;
  const int rBase = wm * 64, cBase = wn * 64;
  const int l15 = lane & 15, ka = (lane >> 4) * 8, rj = (lane >> 4) * 4;
  const int nBase = blockIdx.x * 256;

  f32x4 acc[4][4];
#pragma unroll
  for (int mi = 0; mi < 4; ++mi)
#pragma unroll
    for (int ni = 0; ni < 4; ++ni) acc[mi][ni] = (f32x4){0.f, 0.f, 0.f, 0.f};
#pragma unroll
  for (int kk = 0; kk < 8; ++kk) {
    const int k0 = kk * 32 + ka;
    bf16x8 a[4], b[4];
#pragma unroll
    for (int mi = 0; mi < 4; ++mi) {
      int n = nBase + rBase + mi * 16 + l15;
      if (n > N_NODES - 1) n = N_NODES - 1;
      const float* src = (kk < 4) ? (nodes + (size_t)n * FEAT + k0)
                                  : (inbox + (size_t)n * FEAT + (k0 - 128));
      a[mi] = cvt_f32x8_bf16(src);
    }
#pragma unroll
    for (int ni = 0; ni < 4; ++ni) {
      int c = cBase + ni * 16 + l15;
      b[ni] = *(const bf16x8*)(wn1t + (size_t)c * 256 + k0);
    }
#pragma unroll
    for (int mi = 0; mi < 4; ++mi)
#pragma unroll
      for (int ni = 0; ni < 4; ++ni)
        acc[mi][ni] = __builtin_amdgcn_mfma_f32_16x16x32_bf16(a[mi], b[ni], acc[mi][ni], 0, 0, 0);
  }
#pragma unroll
  for (int mi = 0; mi < 4; ++mi)
#pragma unroll
    for (int ni = 0; ni < 4; ++ni) {
      int c = cBase + ni * 16 + l15;
      float bias = nb1[c];
#pragma unroll
      for (int j = 0; j < 4; ++j) {
        int r = rBase + mi * 16 + rj + j;
        float v = acc[mi][ni][j] + bias;
        v = v > 0.f ? v : 0.f;
        int byte = r * 256 + ((c * 2) ^ ((r & 7) << 4));
        *(bf16*)((char*)h1 + byte) = (bf16)v;
      }
    }
  __syncthreads();

#pragma unroll
  for (int mi = 0; mi < 4; ++mi)
#pragma unroll
    for (int ni = 0; ni < 4; ++ni) acc[mi][ni] = (f32x4){0.f, 0.f, 0.f, 0.f};
#pragma unroll
  for (int kk = 0; kk < 4; ++kk) {
    const int k0 = kk * 32 + ka;
    bf16x8 a[4], b[4];
#pragma unroll
    for (int mi = 0; mi < 4; ++mi) {
      int r = rBase + mi * 16 + l15;
      int byte = r * 256 + ((k0 * 2) ^ ((r & 7) << 4));
      a[mi] = *(const bf16x8*)((const char*)h1 + byte);
    }
#pragma unroll
    for (int ni = 0; ni < 4; ++ni) {
      int c = cBase + ni * 16 + l15;
      b[ni] = *(const bf16x8*)(wn2t + (size_t)c * 128 + k0);
    }
#pragma unroll
    for (int mi = 0; mi < 4; ++mi)
#pragma unroll
      for (int ni = 0; ni < 4; ++ni)
        acc[mi][ni] = __builtin_amdgcn_mfma_f32_16x16x32_bf16(a[mi], b[ni], acc[mi][ni], 0, 0, 0);
  }
#pragma unroll
  for (int mi = 0; mi < 4; ++mi)
#pragma unroll
    for (int ni = 0; ni < 4; ++ni) {
      int c = cBase + ni * 16 + l15;
      float bias = nb2[c];
#pragma unroll
      for (int j = 0; j < 4; ++j) {
        int r = rBase + mi * 16 + rj + j;
        float v = acc[mi][ni][j] + bias;
        v = v > 0.f ? v : 0.f;
        int byte = r * 256 + ((c * 2) ^ ((r & 7) << 4));
        *(bf16*)((char*)h2 + byte) = (bf16)v;
      }
    }
  __syncthreads();

#pragma unroll
  for (int mi = 0; mi < 4; ++mi)
#pragma unroll
    for (int ni = 0; ni < 4; ++ni) acc[mi][ni] = (f32x4){0.f, 0.f, 0.f, 0.f};
#pragma unroll
  for (int kk = 0; kk < 4; ++kk) {
    const int k0 = kk * 32 + ka;
    bf16x8 a[4], b[4];
#pragma unroll
    for (int mi = 0; mi < 4; ++mi) {
      int r = rBase + mi * 16 + l15;
      int byte = r * 256 + ((k0 * 2) ^ ((r & 7) << 4));
      a[mi] = *(const bf16x8*)((const char*)h2 + byte);
    }
#pragma unroll
    for (int ni = 0; ni < 4; ++ni) {
      int c = cBase + ni * 16 + l15;
      b[ni] = *(const bf16x8*)(wn3t + (size_t)c * 128 + k0);
    }
#pragma unroll
    for (int mi = 0; mi < 4; ++mi)
#pragma unroll
      for (int ni = 0; ni < 4; ++ni)
        acc[mi][ni] = __builtin_amdgcn_mfma_f32_16x16x32_bf16(a[mi], b[ni], acc[mi][ni], 0, 0, 0);
  }
#pragma unroll
  for (int mi = 0; mi < 4; ++mi)
#pragma unroll
    for (int ni = 0; ni < 4; ++ni) {
      int c = cBase + ni * 16 + l15;
      float bias = nb3[c];
#pragma unroll
      for (int j = 0; j < 4; ++j) {
        int r = rBase + mi * 16 + rj + j;
        int n = nBase + r;
        if (n < N_NODES)
          out[(size_t)n * FEAT + c] = nodes[(size_t)n * FEAT + c] + acc[mi][ni][j] + bias;
      }
    }
}

extern "C" void kernel_launch(void* const* d_in, const int* in_sizes, int n_in,
                              void* d_out, int out_size, void* d_ws, size_t ws_size,
                              hipStream_t stream) {
  const float* nodes = (const float*)d_in[0];
  const int* senders = (const int*)d_in[1];
  const int* receivers = (const int*)d_in[2];
  const float* mw1 = (const float*)d_in[3];
  const float* mb1 = (const float*)d_in[4];
  const float* mw2 = (const float*)d_in[5];
  const float* mb2 = (const float*)d_in[6];
  const float* mw3 = (const float*)d_in[7];
  const float* mb3 = (const float*)d_in[8];
  const float* nw1 = (const float*)d_in[9];
  const float* nb1 = (const float*)d_in[10];
  const float* nw2 = (const float*)d_in[11];
  const float* nb2 = (const float*)d_in[12];
  const float* nw3 = (const float*)d_in[13];
  const float* nb3 = (const float*)d_in[14];
  float* out = (float*)d_out;
  const int E = in_sizes[1];

  char* ws = (char*)d_ws;
  bf16* uv = (bf16*)ws;
  bf16* w = (bf16*)(ws + UV_BYTES);
  char* p = ws + UV_BYTES + W_BYTES;
  float* inbox = (float*)p; p += INBOX_BYTES;

  int* offs = (int*)p; p += ((size_t)(N_NODES + 1) * 4 + 255) & ~255ull;
  int* cnt = (int*)p;  p += ((size_t)N_NODES * 4 + 255) & ~255ull;
  int* cur = (int*)p;  p += ((size_t)N_NODES * 4 + 255) & ~255ull;
  int* pos = (int*)p;  p += ((size_t)E * 4 + 255) & ~255ull;
  bf16* msg = (bf16*)p; p += (size_t)E * FEAT * 2;
  const bool sortPath = ((size_t)(p - ws) <= ws_size);

  prep_weights_kernel<<<(W_TOTAL + 255) / 256, 256, 0, stream>>>(mw1, mw2, mw3, nw1, nw2, nw3, w);
  uv_gemm_kernel<<<(N_NODES + 127) / 128, 512, 0, stream>>>(nodes, w + WUV_OFF, mb1, uv);

  if (sortPath) {
    hipMemsetAsync(cnt, 0, (size_t)N_NODES * 4, stream);
    hipMemsetAsync(cur, 0, (size_t)N_NODES * 4, stream);
    hist_kernel<<<(E + 255) / 256, 256, 0, stream>>>(receivers, cnt, E);
    scan1_kernel<<<NB_SCAN, 1024, 0, stream>>>(cnt, offs, pos);  // pos[0..NB_SCAN) = block sums
    scan2_kernel<<<1, 64, 0, stream>>>(pos);
    scan3_kernel<<<NB_SCAN, 1024, 0, stream>>>(offs, pos, E);
    pos_kernel<<<(E + 255) / 256, 256, 0, stream>>>(receivers, offs, cur, pos, E);
    edge_kernel<true><<<(E + EB - 1) / EB, 256, 0, stream>>>(uv, senders, receivers, pos,
                                                             w + WM2_OFF, w + WM3_OFF, mb2, mb3,
                                                             msg, inbox, E);
    reduce_kernel<<<(N_NODES + 63) / 64, 256, 0, stream>>>(msg, offs, inbox);
  } else {
    hipMemsetAsync(inbox, 0, INBOX_BYTES, stream);
    edge_kernel<false><<<(E + EB - 1) / EB, 256, 0, stream>>>(uv, senders, receivers, nullptr,
                                                              w + WM2_OFF, w + WM3_OFF, mb2, mb3,
                                                              nullptr, inbox, E);
  }
  node_kernel<<<(N_NODES + 255) / 256, 512, 0, stream>>>(nodes, inbox, w + WN1_OFF, w + WN2_OFF,
                                                         w + WN3_OFF, nb1, nb2, nb3, out);
}

// Round 5
// 476.889 us; speedup vs baseline: 1.1308x; 1.0521x over previous
//
#include <hip/hip_runtime.h>
#include <hip/hip_bf16.h>
#include <stdint.h>

typedef __bf16 bf16;
typedef bf16 bf16x8 __attribute__((ext_vector_type(8)));
typedef float f32x4 __attribute__((ext_vector_type(4)));

#define N_NODES 50000
#define FEAT 128
#define NB_SCAN ((N_NODES + 1023) / 1024)   // 49

static constexpr size_t UV_BYTES    = (size_t)N_NODES * 256 * 2;    // 25.6 MB bf16 uv
static constexpr size_t INBOX_BYTES = (size_t)N_NODES * FEAT * 4;   // 25.6 MB f32 inbox

#define WUV_OFF 0        // [256][128]  combined (mw1 top|bottom) transposed
#define WM2_OFF 32768    // [128][128]
#define WM3_OFF 49152    // [128][128]
#define WN1_OFF 65536    // [128][256]
#define WN2_OFF 98304    // [128][128]
#define WN3_OFF 114688   // [128][128]
#define W_TOTAL 131072
static constexpr size_t W_BYTES = (size_t)W_TOTAL * 2;

__device__ __forceinline__ bf16x8 cvt_f32x8_bf16(const float* __restrict__ p) {
  float4 f0 = *(const float4*)p;
  float4 f1 = *(const float4*)(p + 4);
  bf16x8 t;
  t[0] = (bf16)f0.x; t[1] = (bf16)f0.y; t[2] = (bf16)f0.z; t[3] = (bf16)f0.w;
  t[4] = (bf16)f1.x; t[5] = (bf16)f1.y; t[6] = (bf16)f1.z; t[7] = (bf16)f1.w;
  return t;
}

// ---------------- prep: cast+transpose weights to bf16 ----------------
__global__ void prep_weights_kernel(const float* __restrict__ mw1, const float* __restrict__ mw2,
                                    const float* __restrict__ mw3, const float* __restrict__ nw1,
                                    const float* __restrict__ nw2, const float* __restrict__ nw3,
                                    bf16* __restrict__ w) {
  int i = blockIdx.x * blockDim.x + threadIdx.x;
  if (i >= W_TOTAL) return;
  float v;
  if (i < WM2_OFF) {
    int c = i >> 7, k = i & 127;
    v = (c < 128) ? mw1[k * 128 + c] : mw1[(128 + k) * 128 + (c - 128)];
  } else if (i < WM3_OFF) {
    int j = i - WM2_OFF; int c = j >> 7, k = j & 127;
    v = mw2[k * 128 + c];
  } else if (i < WN1_OFF) {
    int j = i - WM3_OFF; int c = j >> 7, k = j & 127;
    v = mw3[k * 128 + c];
  } else if (i < WN2_OFF) {
    int j = i - WN1_OFF; int c = j >> 8, k = j & 255;
    v = nw1[k * 128 + c];
  } else if (i < WN3_OFF) {
    int j = i - WN2_OFF; int c = j >> 7, k = j & 127;
    v = nw2[k * 128 + c];
  } else {
    int j = i - WN3_OFF; int c = j >> 7, k = j & 127;
    v = nw3[k * 128 + c];
  }
  w[i] = (bf16)v;
}

// ---------------- CSR build: hist -> scan(3) -> scatter_ids ----------------
__global__ void hist_kernel(const int* __restrict__ receivers, int* __restrict__ cnt, int E) {
  int i = blockIdx.x * blockDim.x + threadIdx.x;
  if (i < E) atomicAdd(&cnt[receivers[i]], 1);
}

__global__ __launch_bounds__(1024) void scan1_kernel(const int* __restrict__ cnt,
                                                     int* __restrict__ offs,
                                                     int* __restrict__ bsum) {
  __shared__ int s[1024];
  const int tid = threadIdx.x;
  const int g = blockIdx.x * 1024 + tid;
  int x = (g < N_NODES) ? cnt[g] : 0;
  s[tid] = x;
  __syncthreads();
  for (int off = 1; off < 1024; off <<= 1) {
    int v = (tid >= off) ? s[tid - off] : 0;
    __syncthreads();
    s[tid] += v;
    __syncthreads();
  }
  if (g < N_NODES) offs[g] = s[tid] - x;
  if (tid == 1023) bsum[blockIdx.x] = s[tid];
}

__global__ void scan2_kernel(int* __restrict__ bsum) {  // 1 block x 64
  __shared__ int s[64];
  const int tid = threadIdx.x;
  int x = (tid < NB_SCAN) ? bsum[tid] : 0;
  s[tid] = x;
  __syncthreads();
  for (int off = 1; off < 64; off <<= 1) {
    int v = (tid >= off) ? s[tid - off] : 0;
    __syncthreads();
    s[tid] += v;
    __syncthreads();
  }
  if (tid < NB_SCAN) bsum[tid] = s[tid] - x;
}

__global__ __launch_bounds__(1024) void scan3_kernel(int* __restrict__ offs,
                                                     const int* __restrict__ bsum, int E) {
  const int tid = threadIdx.x;
  const int g = blockIdx.x * 1024 + tid;
  if (g < N_NODES) offs[g] += bsum[blockIdx.x];
  if (blockIdx.x == 0 && tid == 0) offs[N_NODES] = E;
}

// edges into receiver-sorted slot order
__global__ void scatter_ids_kernel(const int* __restrict__ senders,
                                   const int* __restrict__ receivers,
                                   const int* __restrict__ offs, int* __restrict__ cur,
                                   int* __restrict__ sSend, int* __restrict__ sRecv, int E) {
  int i = blockIdx.x * blockDim.x + threadIdx.x;
  if (i < E) {
    int r = receivers[i];
    int slot = offs[r] + atomicAdd(&cur[r], 1);
    sSend[slot] = senders[i];
    sRecv[slot] = r;
  }
}

// ---------------- uv = nodes @ [W1a | W1b] (+b1 on u-half), bf16 out ----------------
__global__ __launch_bounds__(512) void uv_gemm_kernel(const float* __restrict__ nodes,
                                                      const bf16* __restrict__ wuvt,
                                                      const float* __restrict__ mb1,
                                                      bf16* __restrict__ uv) {
  const int tid = threadIdx.x;
  const int lane = tid & 63, wid = tid >> 6;
  const int wm = wid >> 2, wn = wid & 3;
  const int rBase = blockIdx.x * 128 + wm * 64;
  const int cBase = wn * 64;
  const int l15 = lane & 15, ka = (lane >> 4) * 8, rj = (lane >> 4) * 4;

  f32x4 acc[4][4];
#pragma unroll
  for (int mi = 0; mi < 4; ++mi)
#pragma unroll
    for (int ni = 0; ni < 4; ++ni) acc[mi][ni] = (f32x4){0.f, 0.f, 0.f, 0.f};

#pragma unroll
  for (int kk = 0; kk < 4; ++kk) {
    const int k0 = kk * 32 + ka;
    bf16x8 a[4], b[4];
#pragma unroll
    for (int mi = 0; mi < 4; ++mi) {
      int r = rBase + mi * 16 + l15;
      if (r > N_NODES - 1) r = N_NODES - 1;
      a[mi] = cvt_f32x8_bf16(nodes + (size_t)r * FEAT + k0);
    }
#pragma unroll
    for (int ni = 0; ni < 4; ++ni) {
      int c = cBase + ni * 16 + l15;
      b[ni] = *(const bf16x8*)(wuvt + (size_t)c * 128 + k0);
    }
#pragma unroll
    for (int mi = 0; mi < 4; ++mi)
#pragma unroll
      for (int ni = 0; ni < 4; ++ni)
        acc[mi][ni] = __builtin_amdgcn_mfma_f32_16x16x32_bf16(a[mi], b[ni], acc[mi][ni], 0, 0, 0);
  }
#pragma unroll
  for (int mi = 0; mi < 4; ++mi)
#pragma unroll
    for (int ni = 0; ni < 4; ++ni) {
      int c = cBase + ni * 16 + l15;
      float bias = (c < FEAT) ? mb1[c] : 0.f;
#pragma unroll
      for (int j = 0; j < 4; ++j) {
        int r = rBase + mi * 16 + rj + j;
        if (r < N_NODES) uv[(size_t)r * 256 + c] = (bf16)(acc[mi][ni][j] + bias);
      }
    }
}

// ---------------- edge kernel: sorted slots, fused segmented reduce ----------------
// block: 256 thr = 4 waves; wave owns 32 sorted slots end-to-end.
// gather relu(u[recv]+v[send]) -> MFMA layer2 -> LDS -> MFMA layer3 -> LDS ->
// per-wave segmented sum over receiver runs -> f32 atomicAdd per segment.
#define EB 128
__global__ __launch_bounds__(256, 3) void edge_kernel(const bf16* __restrict__ uv,
                                                      const int* __restrict__ sSend,
                                                      const int* __restrict__ sRecv,
                                                      const bf16* __restrict__ wm2t,
                                                      const bf16* __restrict__ wm3t,
                                                      const float* __restrict__ mb2,
                                                      const float* __restrict__ mb3,
                                                      float* __restrict__ inbox, int E) {
  __shared__ int rIds[EB];
  __shared__ int sIds[EB];
  __shared__ bf16 hbuf[4][32 * 128];  // 8KB per-wave transpose slice

  const int tid = threadIdx.x;
  const int e0 = blockIdx.x * EB;
  const int rMax = (E - e0 < EB) ? (E - e0) : EB;

  if (tid < EB) {
    int e = e0 + tid; if (e >= E) e = E - 1;
    rIds[tid] = sRecv[e];
  } else {
    int t = tid - EB;
    int e = e0 + t; if (e >= E) e = E - 1;
    sIds[t] = sSend[e];
  }
  __syncthreads();

  const int lane = tid & 63, wid = tid >> 6;
  const int l15 = lane & 15, ka = (lane >> 4) * 8, rj = (lane >> 4) * 4;
  const int rW = wid * 32;
  bf16* hw = hbuf[wid];

  // ---- gather A-fragments: afr[mi][kk] = relu(u[recv] + v[send]) ----
  bf16x8 afr[2][4];
#pragma unroll
  for (int mi = 0; mi < 2; ++mi) {
    int row = rW + mi * 16 + l15;
    int recv = rIds[row], send = sIds[row];
    const bf16* up = uv + (size_t)recv * 256;
    const bf16* vp = uv + (size_t)send * 256 + 128;
#pragma unroll
    for (int kk = 0; kk < 4; ++kk) {
      int k0 = kk * 32 + ka;
      bf16x8 u8 = *(const bf16x8*)(up + k0);
      bf16x8 v8 = *(const bf16x8*)(vp + k0);
      bf16x8 h;
#pragma unroll
      for (int t = 0; t < 8; ++t) {
        float x = (float)u8[t] + (float)v8[t];
        h[t] = (bf16)(x > 0.f ? x : 0.f);
      }
      afr[mi][kk] = h;
    }
  }

  // ---- layer 2: acc[2][8] = h1 @ W2 (M=32, N=128, K=128) ----
  f32x4 acc[2][8];
#pragma unroll
  for (int mi = 0; mi < 2; ++mi)
#pragma unroll
    for (int ni = 0; ni < 8; ++ni) acc[mi][ni] = (f32x4){0.f, 0.f, 0.f, 0.f};
#pragma unroll
  for (int kk = 0; kk < 4; ++kk) {
    const int k0 = kk * 32 + ka;
    bf16x8 b[8];
#pragma unroll
    for (int ni = 0; ni < 8; ++ni) {
      int c = ni * 16 + l15;
      b[ni] = *(const bf16x8*)(wm2t + (size_t)c * 128 + k0);
    }
#pragma unroll
    for (int mi = 0; mi < 2; ++mi)
#pragma unroll
      for (int ni = 0; ni < 8; ++ni)
        acc[mi][ni] = __builtin_amdgcn_mfma_f32_16x16x32_bf16(afr[mi][kk], b[ni], acc[mi][ni], 0, 0, 0);
  }

  // ---- epilogue layer2: relu+bias -> bf16 -> wave-private swizzled LDS ----
#pragma unroll
  for (int mi = 0; mi < 2; ++mi)
#pragma unroll
    for (int ni = 0; ni < 8; ++ni) {
      int c = ni * 16 + l15;
      float bias = mb2[c];
#pragma unroll
      for (int j = 0; j < 4; ++j) {
        int row = mi * 16 + rj + j;
        float v = acc[mi][ni][j] + bias;
        v = v > 0.f ? v : 0.f;
        int byte = row * 256 + ((c * 2) ^ ((row & 7) << 4));
        *(bf16*)((char*)hw + byte) = (bf16)v;
      }
    }
  asm volatile("s_waitcnt lgkmcnt(0)" ::: "memory");
  __builtin_amdgcn_sched_barrier(0);

  // ---- layer 3: acc3[2][8] = h2 @ W3 ----
  bf16x8 a3[2][4];
#pragma unroll
  for (int mi = 0; mi < 2; ++mi) {
    int row = mi * 16 + l15;
#pragma unroll
    for (int kk = 0; kk < 4; ++kk) {
      int k0 = kk * 32 + ka;
      int byte = row * 256 + ((k0 * 2) ^ ((row & 7) << 4));
      a3[mi][kk] = *(const bf16x8*)((const char*)hw + byte);
    }
  }
  f32x4 acc3[2][8];
#pragma unroll
  for (int mi = 0; mi < 2; ++mi)
#pragma unroll
    for (int ni = 0; ni < 8; ++ni) acc3[mi][ni] = (f32x4){0.f, 0.f, 0.f, 0.f};
#pragma unroll
  for (int kk = 0; kk < 4; ++kk) {
    const int k0 = kk * 32 + ka;
    bf16x8 b[8];
#pragma unroll
    for (int ni = 0; ni < 8; ++ni) {
      int c = ni * 16 + l15;
      b[ni] = *(const bf16x8*)(wm3t + (size_t)c * 128 + k0);
    }
#pragma unroll
    for (int mi = 0; mi < 2; ++mi)
#pragma unroll
      for (int ni = 0; ni < 8; ++ni)
        acc3[mi][ni] = __builtin_amdgcn_mfma_f32_16x16x32_bf16(a3[mi][kk], b[ni], acc3[mi][ni], 0, 0, 0);
  }

  // ---- write final messages (bias, no relu) to wave-private LDS ----
  asm volatile("s_waitcnt lgkmcnt(0)" ::: "memory");
  __builtin_amdgcn_sched_barrier(0);
#pragma unroll
  for (int mi = 0; mi < 2; ++mi)
#pragma unroll
    for (int ni = 0; ni < 8; ++ni) {
      int c = ni * 16 + l15;
      float bias = mb3[c];
#pragma unroll
      for (int j = 0; j < 4; ++j) {
        int row = mi * 16 + rj + j;
        int byte = row * 256 + ((c * 2) ^ ((row & 7) << 4));
        *(bf16*)((char*)hw + byte) = (bf16)(acc3[mi][ni][j] + bias);
      }
    }
  asm volatile("s_waitcnt lgkmcnt(0)" ::: "memory");
  __builtin_amdgcn_sched_barrier(0);

  // ---- segmented reduce over receiver runs: lane owns cols 2*lane, 2*lane+1 ----
  uint32_t pr[32];
#pragma unroll
  for (int r = 0; r < 32; ++r) {
    int byte = r * 256 + ((4 * lane) ^ ((r & 7) << 4));
    pr[r] = *(const uint32_t*)((const char*)hw + byte);
  }
  const int cb = 2 * lane;
  float s0 = 0.f, s1 = 0.f;
#pragma unroll
  for (int r = 0; r < 32; ++r) {
    int grow = rW + r;
    if (grow >= rMax) break;  // uniform across block
    s0 += __uint_as_float(pr[r] << 16);
    s1 += __uint_as_float(pr[r] & 0xffff0000u);
    int recv = rIds[grow];
    bool flush = (r == 31) || (grow + 1 >= rMax) || (rIds[grow + 1] != recv);
    if (flush) {
      float* dst = inbox + (size_t)recv * FEAT + cb;
      unsafeAtomicAdd(dst, s0);
      unsafeAtomicAdd(dst + 1, s1);
      s0 = 0.f; s1 = 0.f;
    }
  }
}

// ---------------- node kernel: out = nodes + MLP([nodes|inbox]) ----------------
__global__ __launch_bounds__(512) void node_kernel(const float* __restrict__ nodes,
                                                   const float* __restrict__ inbox,
                                                   const bf16* __restrict__ wn1t,
                                                   const bf16* __restrict__ wn2t,
                                                   const bf16* __restrict__ wn3t,
                                                   const float* __restrict__ nb1,
                                                   const float* __restrict__ nb2,
                                                   const float* __restrict__ nb3,
                                                   float* __restrict__ out) {
  __shared__ bf16 h1[256 * 128];
  __shared__ bf16 h2[256 * 128];
  const int tid = threadIdx.x;
  const int lane = tid & 63, wid = tid >> 6;
  const int wm = wid >> 1, wn = wid & 1;
  const int rBase = wm * 64, cBase = wn * 64;
  const int l15 = lane & 15, ka = (lane >> 4) * 8, rj = (lane >> 4) * 4;
  const int nBase = blockIdx.x * 256;

  f32x4 acc[4][4];
#pragma unroll
  for (int mi = 0; mi < 4; ++mi)
#pragma unroll
    for (int ni = 0; ni < 4; ++ni) acc[mi][ni] = (f32x4){0.f, 0.f, 0.f, 0.f};
#pragma unroll
  for (int kk = 0; kk < 8; ++kk) {
    const int k0 = kk * 32 + ka;
    bf16x8 a[4], b[4];
#pragma unroll
    for (int mi = 0; mi < 4; ++mi) {
      int n = nBase + rBase + mi * 16 + l15;
      if (n > N_NODES - 1) n = N_NODES - 1;
      const float* src = (kk < 4) ? (nodes + (size_t)n * FEAT + k0)
                                  : (inbox + (size_t)n * FEAT + (k0 - 128));
      a[mi] = cvt_f32x8_bf16(src);
    }
#pragma unroll
    for (int ni = 0; ni < 4; ++ni) {
      int c = cBase + ni * 16 + l15;
      b[ni] = *(const bf16x8*)(wn1t + (size_t)c * 256 + k0);
    }
#pragma unroll
    for (int mi = 0; mi < 4; ++mi)
#pragma unroll
      for (int ni = 0; ni < 4; ++ni)
        acc[mi][ni] = __builtin_amdgcn_mfma_f32_16x16x32_bf16(a[mi], b[ni], acc[mi][ni], 0, 0, 0);
  }
#pragma unroll
  for (int mi = 0; mi < 4; ++mi)
#pragma unroll
    for (int ni = 0; ni < 4; ++ni) {
      int c = cBase + ni * 16 + l15;
      float bias = nb1[c];
#pragma unroll
      for (int j = 0; j < 4; ++j) {
        int r = rBase + mi * 16 + rj + j;
        float v = acc[mi][ni][j] + bias;
        v = v > 0.f ? v : 0.f;
        int byte = r * 256 + ((c * 2) ^ ((r & 7) << 4));
        *(bf16*)((char*)h1 + byte) = (bf16)v;
      }
    }
  __syncthreads();

#pragma unroll
  for (int mi = 0; mi < 4; ++mi)
#pragma unroll
    for (int ni = 0; ni < 4; ++ni) acc[mi][ni] = (f32x4){0.f, 0.f, 0.f, 0.f};
#pragma unroll
  for (int kk = 0; kk < 4; ++kk) {
    const int k0 = kk * 32 + ka;
    bf16x8 a[4], b[4];
#pragma unroll
    for (int mi = 0; mi < 4; ++mi) {
      int r = rBase + mi * 16 + l15;
      int byte = r * 256 + ((k0 * 2) ^ ((r & 7) << 4));
      a[mi] = *(const bf16x8*)((const char*)h1 + byte);
    }
#pragma unroll
    for (int ni = 0; ni < 4; ++ni) {
      int c = cBase + ni * 16 + l15;
      b[ni] = *(const bf16x8*)(wn2t + (size_t)c * 128 + k0);
    }
#pragma unroll
    for (int mi = 0; mi < 4; ++mi)
#pragma unroll
      for (int ni = 0; ni < 4; ++ni)
        acc[mi][ni] = __builtin_amdgcn_mfma_f32_16x16x32_bf16(a[mi], b[ni], acc[mi][ni], 0, 0, 0);
  }
#pragma unroll
  for (int mi = 0; mi < 4; ++mi)
#pragma unroll
    for (int ni = 0; ni < 4; ++ni) {
      int c = cBase + ni * 16 + l15;
      float bias = nb2[c];
#pragma unroll
      for (int j = 0; j < 4; ++j) {
        int r = rBase + mi * 16 + rj + j;
        float v = acc[mi][ni][j] + bias;
        v = v > 0.f ? v : 0.f;
        int byte = r * 256 + ((c * 2) ^ ((r & 7) << 4));
        *(bf16*)((char*)h2 + byte) = (bf16)v;
      }
    }
  __syncthreads();

#pragma unroll
  for (int mi = 0; mi < 4; ++mi)
#pragma unroll
    for (int ni = 0; ni < 4; ++ni) acc[mi][ni] = (f32x4){0.f, 0.f, 0.f, 0.f};
#pragma unroll
  for (int kk = 0; kk < 4; ++kk) {
    const int k0 = kk * 32 + ka;
    bf16x8 a[4], b[4];
#pragma unroll
    for (int mi = 0; mi < 4; ++mi) {
      int r = rBase + mi * 16 + l15;
      int byte = r * 256 + ((k0 * 2) ^ ((r & 7) << 4));
      a[mi] = *(const bf16x8*)((const char*)h2 + byte);
    }
#pragma unroll
    for (int ni = 0; ni < 4; ++ni) {
      int c = cBase + ni * 16 + l15;
      b[ni] = *(const bf16x8*)(wn3t + (size_t)c * 128 + k0);
    }
#pragma unroll
    for (int mi = 0; mi < 4; ++mi)
#pragma unroll
      for (int ni = 0; ni < 4; ++ni)
        acc[mi][ni] = __builtin_amdgcn_mfma_f32_16x16x32_bf16(a[mi], b[ni], acc[mi][ni], 0, 0, 0);
  }
#pragma unroll
  for (int mi = 0; mi < 4; ++mi)
#pragma unroll
    for (int ni = 0; ni < 4; ++ni) {
      int c = cBase + ni * 16 + l15;
      float bias = nb3[c];
#pragma unroll
      for (int j = 0; j < 4; ++j) {
        int r = rBase + mi * 16 + rj + j;
        int n = nBase + r;
        if (n < N_NODES)
          out[(size_t)n * FEAT + c] = nodes[(size_t)n * FEAT + c] + acc[mi][ni][j] + bias;
      }
    }
}

extern "C" void kernel_launch(void* const* d_in, const int* in_sizes, int n_in,
                              void* d_out, int out_size, void* d_ws, size_t ws_size,
                              hipStream_t stream) {
  const float* nodes = (const float*)d_in[0];
  const int* senders = (const int*)d_in[1];
  const int* receivers = (const int*)d_in[2];
  const float* mw1 = (const float*)d_in[3];
  const float* mb1 = (const float*)d_in[4];
  const float* mw2 = (const float*)d_in[5];
  const float* mb2 = (const float*)d_in[6];
  const float* mw3 = (const float*)d_in[7];
  const float* mb3 = (const float*)d_in[8];
  const float* nw1 = (const float*)d_in[9];
  const float* nb1 = (const float*)d_in[10];
  const float* nw2 = (const float*)d_in[11];
  const float* nb2 = (const float*)d_in[12];
  const float* nw3 = (const float*)d_in[13];
  const float* nb3 = (const float*)d_in[14];
  float* out = (float*)d_out;
  const int E = in_sizes[1];

  char* ws = (char*)d_ws;
  bf16* uv = (bf16*)ws;
  bf16* w = (bf16*)(ws + UV_BYTES);
  char* p = ws + UV_BYTES + W_BYTES;
  float* inbox = (float*)p; p += INBOX_BYTES;
  int* offs = (int*)p; p += ((size_t)(N_NODES + 1) * 4 + 255) & ~255ull;
  int* cnt = (int*)p;  p += ((size_t)N_NODES * 4 + 255) & ~255ull;
  int* cur = (int*)p;  p += ((size_t)N_NODES * 4 + 255) & ~255ull;
  int* bsum = (int*)p; p += 256;
  int* sSend = (int*)p; p += ((size_t)E * 4 + 255) & ~255ull;
  int* sRecv = (int*)p; p += ((size_t)E * 4 + 255) & ~255ull;

  // CSR build + sorted id arrays
  hipMemsetAsync(cnt, 0, (size_t)N_NODES * 4, stream);
  hipMemsetAsync(cur, 0, (size_t)N_NODES * 4, stream);
  hipMemsetAsync(inbox, 0, INBOX_BYTES, stream);
  prep_weights_kernel<<<(W_TOTAL + 255) / 256, 256, 0, stream>>>(mw1, mw2, mw3, nw1, nw2, nw3, w);
  hist_kernel<<<(E + 255) / 256, 256, 0, stream>>>(receivers, cnt, E);
  scan1_kernel<<<NB_SCAN, 1024, 0, stream>>>(cnt, offs, bsum);
  scan2_kernel<<<1, 64, 0, stream>>>(bsum);
  scan3_kernel<<<NB_SCAN, 1024, 0, stream>>>(offs, bsum, E);
  scatter_ids_kernel<<<(E + 255) / 256, 256, 0, stream>>>(senders, receivers, offs, cur,
                                                          sSend, sRecv, E);
  uv_gemm_kernel<<<(N_NODES + 127) / 128, 512, 0, stream>>>(nodes, w + WUV_OFF, mb1, uv);
  edge_kernel<<<(E + EB - 1) / EB, 256, 0, stream>>>(uv, sSend, sRecv, w + WM2_OFF, w + WM3_OFF,
                                                     mb2, mb3, inbox, E);
  node_kernel<<<(N_NODES + 255) / 256, 512, 0, stream>>>(nodes, inbox, w + WN1_OFF, w + WN2_OFF,
                                                         w + WN3_OFF, nb1, nb2, nb3, out);
}